// Round 20
// baseline (361.392 us; speedup 1.0000x reference)
//
#include <hip/hip_runtime.h>
#include <math.h>

#define B_TOTAL 8192
#define C_DIM 62
#define CC (C_DIM * C_DIM)   // 3844 floats
#define EPSV 1e-4f
#define NSWEEP 4
#define WSTRIDE 72
#define YSTR 9
#define NREP 8

// ---------- V0: hybrid DPP(1-3)/swizzle(4-7) ----------
template<int M> __device__ __forceinline__ float sx(float x) {
  int xi = __builtin_bit_cast(int, x);
  int r;
  if constexpr (M == 1)      r = __builtin_amdgcn_update_dpp(xi, xi, 0xB1, 0xF, 0xF, false);
  else if constexpr (M == 2) r = __builtin_amdgcn_update_dpp(xi, xi, 0x4E, 0xF, 0xF, false);
  else if constexpr (M == 3) r = __builtin_amdgcn_update_dpp(xi, xi, 0x1B, 0xF, 0xF, false);
  else                       r = __builtin_amdgcn_ds_swizzle(xi, (M << 10) | 0x1F);
  return __builtin_bit_cast(float, r);
}
// ---------- V2: all-DPP (R10 style) ----------
template<int M> __device__ __forceinline__ float sx_dpp(float x) {
  int xi = __builtin_bit_cast(int, x);
  int r;
  if constexpr (M == 1)      r = __builtin_amdgcn_update_dpp(xi, xi, 0xB1, 0xF, 0xF, false);
  else if constexpr (M == 2) r = __builtin_amdgcn_update_dpp(xi, xi, 0x4E, 0xF, 0xF, false);
  else if constexpr (M == 3) r = __builtin_amdgcn_update_dpp(xi, xi, 0x1B, 0xF, 0xF, false);
  else if constexpr (M == 7) r = __builtin_amdgcn_update_dpp(xi, xi, 0x141, 0xF, 0xF, false);
  else {
    int t = __builtin_amdgcn_update_dpp(xi, xi, 0x141, 0xF, 0xF, false);
    constexpr int Q = 7 ^ M;
    constexpr int ctrl = (Q == 1) ? 0xB1 : (Q == 2) ? 0x4E : 0x1B;
    r = __builtin_amdgcn_update_dpp(t, t, ctrl, 0xF, 0xF, false);
  }
  return __builtin_bit_cast(float, r);
}
// variant dispatcher: V1 = identity (comm deleted, chains preserved)
template<int VAR, int M> __device__ __forceinline__ float sxv(float x) {
  if constexpr (VAR == 0) return sx<M>(x);
  else if constexpr (VAR == 1) return x;
  else return sx_dpp<M>(x);
}

__device__ __forceinline__ void xperm8(float r[8], const int e) {
  const bool b0 = (e & 1) != 0, b1 = (e & 2) != 0, b2 = (e & 4) != 0;
  float t0[8], t1[8];
#pragma unroll
  for (int j = 0; j < 8; ++j) t0[j] = b0 ? r[j ^ 1] : r[j];
#pragma unroll
  for (int j = 0; j < 8; ++j) t1[j] = b1 ? t0[j ^ 2] : t0[j];
#pragma unroll
  for (int j = 0; j < 8; ++j) r[j] = b2 ? t1[j ^ 4] : t1[j];
}

template<int VAR, int M>
__device__ __forceinline__ void jstage(float ar[8], float pr[8], const int e) {
  constexpr int HB = (M >= 4) ? 4 : ((M >= 2) ? 2 : 1);
  constexpr int A1 = (M == 1) ? 2 : 1;
  constexpr int A2 = (M <= 3) ? 4 : 2;
  const bool low = (e & HB) == 0;
  float d_oth = sxv<VAR, M>(ar[0]);
  float o_oth = sxv<VAR, M>(ar[M]);
  float apq = 0.5f * (ar[M] + o_oth);
  float app = low ? ar[0] : d_oth;
  float aqq = low ? d_oth : ar[0];
  float taun = aqq - app;
  float den = fabsf(taun) + sqrtf(fmaf(taun, taun, 4.f * apq * apq)) + 1e-38f;
  float t = (2.f * apq) * copysignf(1.f, taun) * __builtin_amdgcn_rcpf(den);
  float c = rsqrtf(fmaf(t, t, 1.f));
  float s = t * c;
  float cg[8], sg[8];
  cg[0] = c;  sg[0] = s;
  cg[A1] = sxv<VAR, A1>(c);  sg[A1] = sxv<VAR, A1>(s);
  cg[A2] = sxv<VAR, A2>(c);  sg[A2] = sxv<VAR, A2>(s);
  cg[A1 ^ A2] = sxv<VAR, A2>(cg[A1]);  sg[A1 ^ A2] = sxv<VAR, A2>(sg[A1]);
  float an[8], pn[8];
#pragma unroll
  for (int d = 0; d < 8; ++d) {
    constexpr int T0 = 0;
    const int rep = (d == T0 || d == A1 || d == A2 || d == (A1 ^ A2)) ? d : (d ^ M);
    const bool flip = (d & HB) != 0;
    float sD = sg[rep];
    float ss = (low != flip) ? -sD : sD;
    an[d] = fmaf(cg[rep], ar[d], ss * ar[d ^ M]);
    pn[d] = fmaf(cg[rep], pr[d], ss * pr[d ^ M]);
  }
#pragma unroll
  for (int d = 0; d < 8; ++d) pr[d] = pn[d];
  float scol = low ? -s : s;
  float aoth[8];
#pragma unroll
  for (int d = 0; d < 8; ++d) aoth[d] = sxv<VAR, M>(an[d ^ M]);
#pragma unroll
  for (int d = 0; d < 8; ++d) ar[d] = fmaf(c, an[d], scol * aoth[d]);
}

template<int VAR>
__device__ __forceinline__ void jacobi8rel(float ar[8], float u[8], const int e) {
  float pr[8];
#pragma unroll
  for (int i = 0; i < 8; ++i) pr[i] = (i == 0) ? 1.f : 0.f;
#pragma unroll 1
  for (int sweep = 0; sweep < NSWEEP; ++sweep) {
    jstage<VAR, 1>(ar, pr, e);
    jstage<VAR, 2>(ar, pr, e);
    jstage<VAR, 3>(ar, pr, e);
    jstage<VAR, 4>(ar, pr, e);
    jstage<VAR, 5>(ar, pr, e);
    jstage<VAR, 6>(ar, pr, e);
    jstage<VAR, 7>(ar, pr, e);
  }
  u[0] = pr[0];
  u[1] = sxv<VAR, 1>(pr[1]);
  u[2] = sxv<VAR, 2>(pr[2]);
  u[3] = sxv<VAR, 3>(pr[3]);
  u[4] = sxv<VAR, 4>(pr[4]);
  u[5] = sxv<VAR, 5>(pr[5]);
  u[6] = sxv<VAR, 6>(pr[6]);
  u[7] = sxv<VAR, 7>(pr[7]);
  xperm8(u, e);
}

// ---- shared device body pieces ----
struct SmemT {
  float w1s[C_DIM * 8];
  float Ys[C_DIM * YSTR];
  float M1s[8 * 64];
  float Wbuf[8 * WSTRIDE];
  float lwbuf[64];
  float w2s[64];
  float fcs[128];
};

__device__ __forceinline__ void runA(SmemT* sm, const float* X, const float* w1,
                                     int b0, int lane) {
  float xrA[C_DIM], xrB[C_DIM];
  if (lane < C_DIM) {
    const float* row = X + (size_t)b0 * CC + lane * C_DIM;
#pragma unroll
    for (int k = 0; k < 31; ++k) {
      float2 t = *(const float2*)(row + 2 * k);
      xrA[2 * k] = t.x; xrA[2 * k + 1] = t.y;
    }
  }
  auto loadrow = [&](float* r, int g) {
    if (lane < C_DIM) {
      const float* row = X + (size_t)(b0 + g) * CC + lane * C_DIM;
#pragma unroll
      for (int k = 0; k < 31; ++k) {
        float2 t = *(const float2*)(row + 2 * k);
        r[2 * k] = t.x; r[2 * k + 1] = t.y;
      }
    }
  };
  auto computeA = [&](const float* xr, int g) {
    if (lane < C_DIM) {
      float a0=0.f,a1=0.f,a2=0.f,a3=0.f,a4=0.f,a5=0.f,a6=0.f,a7=0.f;
#pragma unroll
      for (int d = 0; d < C_DIM; ++d) {
        float x = xr[d];
        const float* wr = w1 + d * 8;
        a0 = fmaf(x, wr[0], a0); a1 = fmaf(x, wr[1], a1);
        a2 = fmaf(x, wr[2], a2); a3 = fmaf(x, wr[3], a3);
        a4 = fmaf(x, wr[4], a4); a5 = fmaf(x, wr[5], a5);
        a6 = fmaf(x, wr[6], a6); a7 = fmaf(x, wr[7], a7);
      }
      float* yr = sm->Ys + lane * YSTR;
      yr[0]=a0; yr[1]=a1; yr[2]=a2; yr[3]=a3;
      yr[4]=a4; yr[5]=a5; yr[6]=a6; yr[7]=a7;
    }
    __syncthreads();
    {
      const int a_ = lane >> 3, e_ = lane & 7;
      float s = 0.f;
#pragma unroll
      for (int c = 0; c < C_DIM; ++c)
        s = fmaf(sm->w1s[c * 8 + a_], sm->Ys[c * YSTR + e_], s);
      sm->M1s[g * 64 + lane] = s;
    }
    __syncthreads();
  };
#pragma unroll 1
  for (int g = 0; g < 8; g += 2) {
    loadrow(xrB, g + 1);
    computeA(xrA, g);
    if (g + 2 < 8) loadrow(xrA, g + 2);
    computeA(xrB, g + 1);
  }
}

template<int VAR>
__device__ __forceinline__ void runB(SmemT* sm, float* out, int b0, int lane) {
  const int e = lane & 7;
  const int g = lane >> 3;
  float a[8], u[8], m2[8];
  float* Wg = &sm->Wbuf[g * WSTRIDE];
#pragma unroll
  for (int j = 0; j < 8; ++j) a[j] = sm->M1s[g * 64 + e * 8 + j];
  {
    float t[8];
#pragma unroll
    for (int j = 0; j < 8; ++j) t[j] = 0.f;
#pragma unroll
    for (int k = 0; k < 8; ++k) {
      float4 q0 = *(const float4*)(sm->w2s + k * 8);
      float4 q1 = *(const float4*)(sm->w2s + k * 8 + 4);
      t[0] = fmaf(a[k], q0.x, t[0]); t[1] = fmaf(a[k], q0.y, t[1]);
      t[2] = fmaf(a[k], q0.z, t[2]); t[3] = fmaf(a[k], q0.w, t[3]);
      t[4] = fmaf(a[k], q1.x, t[4]); t[5] = fmaf(a[k], q1.y, t[5]);
      t[6] = fmaf(a[k], q1.z, t[6]); t[7] = fmaf(a[k], q1.w, t[7]);
    }
#pragma unroll
    for (int j = 0; j < 8; ++j) Wg[e * 8 + j] = t[j];
  }
  __syncthreads();
  {
    float tcol[8];
#pragma unroll
    for (int k = 0; k < 8; ++k) tcol[k] = Wg[k * 8 + e];
#pragma unroll
    for (int i = 0; i < 8; ++i) m2[i] = 0.f;
#pragma unroll
    for (int k = 0; k < 8; ++k) {
      float4 q0 = *(const float4*)(sm->w2s + k * 8);
      float4 q1 = *(const float4*)(sm->w2s + k * 8 + 4);
      m2[0] = fmaf(q0.x, tcol[k], m2[0]); m2[1] = fmaf(q0.y, tcol[k], m2[1]);
      m2[2] = fmaf(q0.z, tcol[k], m2[2]); m2[3] = fmaf(q0.w, tcol[k], m2[3]);
      m2[4] = fmaf(q1.x, tcol[k], m2[4]); m2[5] = fmaf(q1.y, tcol[k], m2[5]);
      m2[6] = fmaf(q1.z, tcol[k], m2[6]); m2[7] = fmaf(q1.w, tcol[k], m2[7]);
    }
  }
  __syncthreads();
  xperm8(m2, e);
  jacobi8rel<VAR>(m2, u, e);
  float lw = logf(fmaxf(m2[0], EPSV));
#pragma unroll
  for (int i = 0; i < 8; ++i) Wg[e * 8 + i] = u[i];
  sm->lwbuf[g * 8 + e] = lw;
  __syncthreads();
  {
    float mk[8];
#pragma unroll
    for (int k = 0; k < 8; ++k) mk[k] = sm->lwbuf[g * 8 + k] * Wg[k * 8 + e];
    float fcol[8];
#pragma unroll
    for (int i = 0; i < 8; ++i) fcol[i] = 0.f;
#pragma unroll
    for (int k = 0; k < 8; ++k) {
      float4 q0 = *(const float4*)&Wg[k * 8 + 0];
      float4 q1 = *(const float4*)&Wg[k * 8 + 4];
      fcol[0] = fmaf(q0.x, mk[k], fcol[0]); fcol[1] = fmaf(q0.y, mk[k], fcol[1]);
      fcol[2] = fmaf(q0.z, mk[k], fcol[2]); fcol[3] = fmaf(q0.w, mk[k], fcol[3]);
      fcol[4] = fmaf(q1.x, mk[k], fcol[4]); fcol[5] = fmaf(q1.y, mk[k], fcol[5]);
      fcol[6] = fmaf(q1.z, mk[k], fcol[6]); fcol[7] = fmaf(q1.w, mk[k], fcol[7]);
    }
    float l0 = 0.f, l1 = 0.f;
    const int b = b0 + g;
    float* featg = out + 2 * (size_t)B_TOTAL + (size_t)b * 64;
#pragma unroll
    for (int i = 0; i < 8; ++i) {
      featg[i * 8 + e] = fcol[i];
      l0 = fmaf(fcol[i], sm->fcs[(i * 8 + e) * 2 + 0], l0);
      l1 = fmaf(fcol[i], sm->fcs[(i * 8 + e) * 2 + 1], l1);
    }
    l0 += sx<1>(l0); l0 += sx<2>(l0); l0 += sx<4>(l0);
    l1 += sx<1>(l1); l1 += sx<2>(l1); l1 += sx<4>(l1);
    float mx = fmaxf(l0, l1);
    float lse = mx + logf(expf(l0 - mx) + expf(l1 - mx));
    if (e < 2) out[(size_t)b * 2 + e] = (e ? l1 : l0) - lse;
  }
}

// ================= real kernel (V0, R18-equivalent) =================
__global__ __launch_bounds__(64) void spdnet_kernel(
    const float* __restrict__ X, const float* __restrict__ w1,
    const float* __restrict__ w2, const float* __restrict__ fc,
    float* __restrict__ out) {
  __shared__ SmemT sm;
  const int lane = threadIdx.x;
  const int b0 = blockIdx.x * 8;
  sm.w2s[lane] = w2[lane];
  sm.fcs[lane] = fc[lane];
  sm.fcs[lane + 64] = fc[lane + 64];
  if (lane < C_DIM) {
    *(float4*)(sm.w1s + lane * 8)     = *(const float4*)(w1 + lane * 8);
    *(float4*)(sm.w1s + lane * 8 + 4) = *(const float4*)(w1 + lane * 8 + 4);
  }
  __syncthreads();
  runA(&sm, X, w1, b0, lane);
  runB<0>(&sm, out, b0, lane);
}

// ================= probe: A x1 + B x NREP =================
template<int VAR>
__global__ __launch_bounds__(64) void spdnet_probeB(
    const float* __restrict__ X, const float* __restrict__ w1,
    const float* __restrict__ w2, const float* __restrict__ fc,
    float* __restrict__ outbuf) {
  __shared__ SmemT sm;
  const int lane = threadIdx.x;
  const int b0 = blockIdx.x * 8;
  sm.w2s[lane] = w2[lane];
  sm.fcs[lane] = fc[lane];
  sm.fcs[lane + 64] = fc[lane + 64];
  if (lane < C_DIM) {
    *(float4*)(sm.w1s + lane * 8)     = *(const float4*)(w1 + lane * 8);
    *(float4*)(sm.w1s + lane * 8 + 4) = *(const float4*)(w1 + lane * 8 + 4);
  }
  __syncthreads();
  runA(&sm, X, w1, b0, lane);
#pragma unroll 1
  for (int rep = 0; rep < NREP; ++rep) {
    runB<VAR>(&sm, outbuf, b0, lane);
    // serialize reps via a tiny LDS dependency
    sm.M1s[(rep * 64 + lane) & 511] += 1e-30f * sm.lwbuf[lane & 63];
    __syncthreads();
  }
}

extern "C" void kernel_launch(void* const* d_in, const int* in_sizes, int n_in,
                              void* d_out, int out_size, void* d_ws, size_t ws_size,
                              hipStream_t stream) {
  const float* X  = (const float*)d_in[0];
  const float* w1 = (const float*)d_in[1];
  const float* w2 = (const float*)d_in[2];
  const float* fc = (const float*)d_in[3];
  float* out = (float*)d_out;
  float* ws0 = (float*)d_ws;
  float* ws1 = (float*)((char*)d_ws + (16u << 20));
  float* ws2 = (float*)((char*)d_ws + (32u << 20));

  spdnet_probeB<0><<<B_TOTAL / 8, 64, 0, stream>>>(X, w1, w2, fc, ws0);
  spdnet_probeB<1><<<B_TOTAL / 8, 64, 0, stream>>>(X, w1, w2, fc, ws1);
  spdnet_probeB<2><<<B_TOTAL / 8, 64, 0, stream>>>(X, w1, w2, fc, ws2);
  spdnet_kernel<<<B_TOTAL / 8, 64, 0, stream>>>(X, w1, w2, fc, out);
}

// Round 21
// 47.093 us; speedup vs baseline: 7.6740x; 7.6740x over previous
//
#include <hip/hip_runtime.h>
#include <math.h>

#define B_TOTAL 8192
#define C_DIM 62
#define CC (C_DIM * C_DIM)   // 3844 floats
#define EPSV 1e-4f
#define NSWEEP 4
#define NBB 16               // batches per block (2 waves x 8 in A; 8 pairs in B)
#define WSTRIDE 72
#define YSTR 9

// ---------- cross-lane xor-shuffle: DPP (VALU) for masks 1..3, swizzle 4..7 ----------
template<int M> __device__ __forceinline__ float sx(float x) {
  int xi = __builtin_bit_cast(int, x);
  int r;
  if constexpr (M == 1)      r = __builtin_amdgcn_update_dpp(xi, xi, 0xB1, 0xF, 0xF, false);
  else if constexpr (M == 2) r = __builtin_amdgcn_update_dpp(xi, xi, 0x4E, 0xF, 0xF, false);
  else if constexpr (M == 3) r = __builtin_amdgcn_update_dpp(xi, xi, 0x1B, 0xF, 0xF, false);
  else                       r = __builtin_amdgcn_ds_swizzle(xi, (M << 10) | 0x1F);
  return __builtin_bit_cast(float, r);
}

// in-register xor-permute: r[j] <- r[j ^ e]
__device__ __forceinline__ void xperm8(float r[8], const int e) {
  const bool b0 = (e & 1) != 0, b1 = (e & 2) != 0, b2 = (e & 4) != 0;
  float t0[8], t1[8];
#pragma unroll
  for (int j = 0; j < 8; ++j) t0[j] = b0 ? r[j ^ 1] : r[j];
#pragma unroll
  for (int j = 0; j < 8; ++j) t1[j] = b1 ? t0[j ^ 2] : t0[j];
#pragma unroll
  for (int j = 0; j < 8; ++j) r[j] = b2 ? t1[j ^ 4] : t1[j];
}

// ---------- one tournament stage on TWO independent states (ILP-2) ----------
// lane e stores ar[d] = A[e^d][e], pr[d] = P[e^d][e] (P = U^T). The two
// batches' chains are interleaved so comm-latency bubbles of one are filled
// by the other (R20 probe: comm ops are ~95% of single-chain B time).
template<int M>
__device__ __forceinline__ void jstage2(float ar1[8], float pr1[8],
                                        float ar2[8], float pr2[8], const int e) {
  constexpr int HB = (M >= 4) ? 4 : ((M >= 2) ? 2 : 1);
  constexpr int A1 = (M == 1) ? 2 : 1;
  constexpr int A2 = (M <= 3) ? 4 : 2;
  const bool low = (e & HB) == 0;
  float d1 = sx<M>(ar1[0]);
  float d2 = sx<M>(ar2[0]);
  float o1 = sx<M>(ar1[M]);
  float o2 = sx<M>(ar2[M]);
  float apq1 = 0.5f * (ar1[M] + o1);
  float apq2 = 0.5f * (ar2[M] + o2);
  float app1 = low ? ar1[0] : d1, aqq1 = low ? d1 : ar1[0];
  float app2 = low ? ar2[0] : d2, aqq2 = low ? d2 : ar2[0];
  float tn1 = aqq1 - app1;
  float tn2 = aqq2 - app2;
  float den1 = fabsf(tn1) + sqrtf(fmaf(tn1, tn1, 4.f * apq1 * apq1)) + 1e-38f;
  float den2 = fabsf(tn2) + sqrtf(fmaf(tn2, tn2, 4.f * apq2 * apq2)) + 1e-38f;
  float t1 = (2.f * apq1) * copysignf(1.f, tn1) * __builtin_amdgcn_rcpf(den1);
  float t2 = (2.f * apq2) * copysignf(1.f, tn2) * __builtin_amdgcn_rcpf(den2);
  float c1 = rsqrtf(fmaf(t1, t1, 1.f));
  float c2 = rsqrtf(fmaf(t2, t2, 1.f));
  float s1 = t1 * c1;
  float s2 = t2 * c2;
  float cg1[8], sg1[8], cg2[8], sg2[8];
  cg1[0] = c1; sg1[0] = s1; cg2[0] = c2; sg2[0] = s2;
  cg1[A1] = sx<A1>(c1); cg2[A1] = sx<A1>(c2);
  sg1[A1] = sx<A1>(s1); sg2[A1] = sx<A1>(s2);
  cg1[A2] = sx<A2>(c1); cg2[A2] = sx<A2>(c2);
  sg1[A2] = sx<A2>(s1); sg2[A2] = sx<A2>(s2);
  cg1[A1 ^ A2] = sx<A2>(cg1[A1]); cg2[A1 ^ A2] = sx<A2>(cg2[A1]);
  sg1[A1 ^ A2] = sx<A2>(sg1[A1]); sg2[A1 ^ A2] = sx<A2>(sg2[A1]);
  float an1[8], pn1[8], an2[8], pn2[8];
#pragma unroll
  for (int d = 0; d < 8; ++d) {
    const int rep = (d == 0 || d == A1 || d == A2 || d == (A1 ^ A2)) ? d : (d ^ M);
    const bool flip = (d & HB) != 0;
    float ss1 = (low != flip) ? -sg1[rep] : sg1[rep];
    float ss2 = (low != flip) ? -sg2[rep] : sg2[rep];
    an1[d] = fmaf(cg1[rep], ar1[d], ss1 * ar1[d ^ M]);
    an2[d] = fmaf(cg2[rep], ar2[d], ss2 * ar2[d ^ M]);
    pn1[d] = fmaf(cg1[rep], pr1[d], ss1 * pr1[d ^ M]);
    pn2[d] = fmaf(cg2[rep], pr2[d], ss2 * pr2[d ^ M]);
  }
#pragma unroll
  for (int d = 0; d < 8; ++d) { pr1[d] = pn1[d]; pr2[d] = pn2[d]; }
  float sc1 = low ? -s1 : s1;
  float sc2 = low ? -s2 : s2;
  float ao1[8], ao2[8];
#pragma unroll
  for (int d = 0; d < 8; ++d) { ao1[d] = sx<M>(an1[d ^ M]); ao2[d] = sx<M>(an2[d ^ M]); }
#pragma unroll
  for (int d = 0; d < 8; ++d) {
    ar1[d] = fmaf(c1, an1[d], sc1 * ao1[d]);
    ar2[d] = fmaf(c2, an2[d], sc2 * ao2[d]);
  }
}

__device__ __forceinline__ void jacobi8rel2(float ar1[8], float u1[8],
                                            float ar2[8], float u2[8], const int e) {
  float pr1[8], pr2[8];
#pragma unroll
  for (int i = 0; i < 8; ++i) { pr1[i] = (i == 0) ? 1.f : 0.f; pr2[i] = pr1[i]; }
#pragma unroll 1
  for (int sweep = 0; sweep < NSWEEP; ++sweep) {
    jstage2<1>(ar1, pr1, ar2, pr2, e);
    jstage2<2>(ar1, pr1, ar2, pr2, e);
    jstage2<3>(ar1, pr1, ar2, pr2, e);
    jstage2<4>(ar1, pr1, ar2, pr2, e);
    jstage2<5>(ar1, pr1, ar2, pr2, e);
    jstage2<6>(ar1, pr1, ar2, pr2, e);
    jstage2<7>(ar1, pr1, ar2, pr2, e);
  }
  u1[0] = pr1[0];                u2[0] = pr2[0];
  u1[1] = sx<1>(pr1[1]);         u2[1] = sx<1>(pr2[1]);
  u1[2] = sx<2>(pr1[2]);         u2[2] = sx<2>(pr2[2]);
  u1[3] = sx<3>(pr1[3]);         u2[3] = sx<3>(pr2[3]);
  u1[4] = sx<4>(pr1[4]);         u2[4] = sx<4>(pr2[4]);
  u1[5] = sx<5>(pr1[5]);         u2[5] = sx<5>(pr2[5]);
  u1[6] = sx<6>(pr1[6]);         u2[6] = sx<6>(pr2[6]);
  u1[7] = sx<7>(pr1[7]);         u2[7] = sx<7>(pr2[7]);
  xperm8(u1, e);
  xperm8(u2, e);
}

// ---------------- fused kernel: 128 threads = 2 waves, 16 batches ----------------
__global__ __launch_bounds__(128) void spdnet_kernel(
    const float* __restrict__ X, const float* __restrict__ w1,
    const float* __restrict__ w2, const float* __restrict__ fc,
    float* __restrict__ out) {
  __shared__ __align__(16) float w1s[C_DIM * 8];
  __shared__ float Ys[2][C_DIM * YSTR];   // one per wave
  __shared__ float M1s[NBB * 64];
  __shared__ __align__(16) float Wbuf[NBB * WSTRIDE];
  __shared__ float lwbuf[NBB * 8];
  __shared__ float w2s[64];
  __shared__ float fcs[128];
  const int tid = threadIdx.x;
  const int lane = tid & 63;
  const int wv = tid >> 6;          // 0 or 1
  const int b0 = blockIdx.x * NBB;
  const int b0w = b0 + wv * 8;      // this wave's A-batches

  if (tid < 64) w2s[tid] = w2[tid];
  fcs[tid] = fc[tid];
  if (tid < C_DIM) {
    *(float4*)(w1s + tid * 8)     = *(const float4*)(w1 + tid * 8);
    *(float4*)(w1s + tid * 8 + 4) = *(const float4*)(w1 + tid * 8 + 4);
  }

  // ---- A phase: each wave does its 8 batches (R18 structure, own Ys) ----
  float xrA[C_DIM], xrB[C_DIM];
  if (lane < C_DIM) {
    const float* row = X + (size_t)b0w * CC + lane * C_DIM;
#pragma unroll
    for (int k = 0; k < 31; ++k) {
      float2 t = *(const float2*)(row + 2 * k);
      xrA[2 * k] = t.x; xrA[2 * k + 1] = t.y;
    }
  }
  __syncthreads();

  auto loadrow = [&](float* r, int g) {
    if (lane < C_DIM) {
      const float* row = X + (size_t)(b0w + g) * CC + lane * C_DIM;
#pragma unroll
      for (int k = 0; k < 31; ++k) {
        float2 t = *(const float2*)(row + 2 * k);
        r[2 * k] = t.x; r[2 * k + 1] = t.y;
      }
    }
  };
  auto computeA = [&](const float* xr, int g) {
    if (lane < C_DIM) {
      float a0=0.f,a1=0.f,a2=0.f,a3=0.f,a4=0.f,a5=0.f,a6=0.f,a7=0.f;
#pragma unroll
      for (int d = 0; d < C_DIM; ++d) {
        float x = xr[d];
        const float* wr = w1 + d * 8;   // wave-uniform -> scalar path
        a0 = fmaf(x, wr[0], a0); a1 = fmaf(x, wr[1], a1);
        a2 = fmaf(x, wr[2], a2); a3 = fmaf(x, wr[3], a3);
        a4 = fmaf(x, wr[4], a4); a5 = fmaf(x, wr[5], a5);
        a6 = fmaf(x, wr[6], a6); a7 = fmaf(x, wr[7], a7);
      }
      float* yr = Ys[wv] + lane * YSTR;
      yr[0]=a0; yr[1]=a1; yr[2]=a2; yr[3]=a3;
      yr[4]=a4; yr[5]=a5; yr[6]=a6; yr[7]=a7;
    }
    __syncthreads();
    {
      const int a_ = lane >> 3, e_ = lane & 7;
      float s = 0.f;
#pragma unroll
      for (int c = 0; c < C_DIM; ++c)
        s = fmaf(w1s[c * 8 + a_], Ys[wv][c * YSTR + e_], s);
      M1s[(wv * 8 + g) * 64 + lane] = s;
    }
    __syncthreads();
  };

#pragma unroll 1
  for (int g = 0; g < 8; g += 2) {
    loadrow(xrB, g + 1);
    computeA(xrA, g);
    if (g + 2 < 8) loadrow(xrA, g + 2);
    computeA(xrB, g + 1);
  }

  // ---- B phase: wave 0 handles all 16 batches as 8 ILP-2 pairs ----
  const int e = lane & 7;
  const int gg = lane >> 3;          // pair id 0..7 -> batches (gg, gg+8)
  float a1r[8], a2r[8], u1[8], u2[8], m21[8], m22[8];
  float* Wg1 = &Wbuf[gg * WSTRIDE];
  float* Wg2 = &Wbuf[(gg + 8) * WSTRIDE];

  if (wv == 0) {
#pragma unroll
    for (int j = 0; j < 8; ++j) {
      a1r[j] = M1s[gg * 64 + e * 8 + j];
      a2r[j] = M1s[(gg + 8) * 64 + e * 8 + j];
    }
    // T = M1 * w2 for both batches (rec(M1)=M1)
    float t1[8], t2[8];
#pragma unroll
    for (int j = 0; j < 8; ++j) { t1[j] = 0.f; t2[j] = 0.f; }
#pragma unroll
    for (int k = 0; k < 8; ++k) {
      float4 q0 = *(const float4*)(w2s + k * 8);
      float4 q1 = *(const float4*)(w2s + k * 8 + 4);
      t1[0] = fmaf(a1r[k], q0.x, t1[0]); t2[0] = fmaf(a2r[k], q0.x, t2[0]);
      t1[1] = fmaf(a1r[k], q0.y, t1[1]); t2[1] = fmaf(a2r[k], q0.y, t2[1]);
      t1[2] = fmaf(a1r[k], q0.z, t1[2]); t2[2] = fmaf(a2r[k], q0.z, t2[2]);
      t1[3] = fmaf(a1r[k], q0.w, t1[3]); t2[3] = fmaf(a2r[k], q0.w, t2[3]);
      t1[4] = fmaf(a1r[k], q1.x, t1[4]); t2[4] = fmaf(a2r[k], q1.x, t2[4]);
      t1[5] = fmaf(a1r[k], q1.y, t1[5]); t2[5] = fmaf(a2r[k], q1.y, t2[5]);
      t1[6] = fmaf(a1r[k], q1.z, t1[6]); t2[6] = fmaf(a2r[k], q1.z, t2[6]);
      t1[7] = fmaf(a1r[k], q1.w, t1[7]); t2[7] = fmaf(a2r[k], q1.w, t2[7]);
    }
#pragma unroll
    for (int j = 0; j < 8; ++j) { Wg1[e * 8 + j] = t1[j]; Wg2[e * 8 + j] = t2[j]; }
  }
  __syncthreads();
  if (wv == 0) {
    float tc1[8], tc2[8];
#pragma unroll
    for (int k = 0; k < 8; ++k) { tc1[k] = Wg1[k * 8 + e]; tc2[k] = Wg2[k * 8 + e]; }
#pragma unroll
    for (int i = 0; i < 8; ++i) { m21[i] = 0.f; m22[i] = 0.f; }
#pragma unroll
    for (int k = 0; k < 8; ++k) {
      float4 q0 = *(const float4*)(w2s + k * 8);
      float4 q1 = *(const float4*)(w2s + k * 8 + 4);
      m21[0] = fmaf(q0.x, tc1[k], m21[0]); m22[0] = fmaf(q0.x, tc2[k], m22[0]);
      m21[1] = fmaf(q0.y, tc1[k], m21[1]); m22[1] = fmaf(q0.y, tc2[k], m22[1]);
      m21[2] = fmaf(q0.z, tc1[k], m21[2]); m22[2] = fmaf(q0.z, tc2[k], m22[2]);
      m21[3] = fmaf(q0.w, tc1[k], m21[3]); m22[3] = fmaf(q0.w, tc2[k], m22[3]);
      m21[4] = fmaf(q1.x, tc1[k], m21[4]); m22[4] = fmaf(q1.x, tc2[k], m22[4]);
      m21[5] = fmaf(q1.y, tc1[k], m21[5]); m22[5] = fmaf(q1.y, tc2[k], m22[5]);
      m21[6] = fmaf(q1.z, tc1[k], m21[6]); m22[6] = fmaf(q1.z, tc2[k], m22[6]);
      m21[7] = fmaf(q1.w, tc1[k], m21[7]); m22[7] = fmaf(q1.w, tc2[k], m22[7]);
    }
  }
  __syncthreads();   // Wbuf reads done before reuse
  if (wv == 0) {
    xperm8(m21, e);
    xperm8(m22, e);
    jacobi8rel2(m21, u1, m22, u2, e);
    float lw1 = logf(fmaxf(m21[0], EPSV));
    float lw2 = logf(fmaxf(m22[0], EPSV));
#pragma unroll
    for (int i = 0; i < 8; ++i) { Wg1[e * 8 + i] = u1[i]; Wg2[e * 8 + i] = u2[i]; }
    lwbuf[gg * 8 + e] = lw1;
    lwbuf[(gg + 8) * 8 + e] = lw2;
  }
  __syncthreads();
  if (wv == 0) {
    float mk1[8], mk2[8];
#pragma unroll
    for (int k = 0; k < 8; ++k) {
      mk1[k] = lwbuf[gg * 8 + k] * Wg1[k * 8 + e];
      mk2[k] = lwbuf[(gg + 8) * 8 + k] * Wg2[k * 8 + e];
    }
    float f1[8], f2[8];
#pragma unroll
    for (int i = 0; i < 8; ++i) { f1[i] = 0.f; f2[i] = 0.f; }
#pragma unroll
    for (int k = 0; k < 8; ++k) {
      float4 q0 = *(const float4*)&Wg1[k * 8 + 0];
      float4 q1 = *(const float4*)&Wg1[k * 8 + 4];
      float4 r0 = *(const float4*)&Wg2[k * 8 + 0];
      float4 r1 = *(const float4*)&Wg2[k * 8 + 4];
      f1[0] = fmaf(q0.x, mk1[k], f1[0]); f2[0] = fmaf(r0.x, mk2[k], f2[0]);
      f1[1] = fmaf(q0.y, mk1[k], f1[1]); f2[1] = fmaf(r0.y, mk2[k], f2[1]);
      f1[2] = fmaf(q0.z, mk1[k], f1[2]); f2[2] = fmaf(r0.z, mk2[k], f2[2]);
      f1[3] = fmaf(q0.w, mk1[k], f1[3]); f2[3] = fmaf(r0.w, mk2[k], f2[3]);
      f1[4] = fmaf(q1.x, mk1[k], f1[4]); f2[4] = fmaf(r1.x, mk2[k], f2[4]);
      f1[5] = fmaf(q1.y, mk1[k], f1[5]); f2[5] = fmaf(r1.y, mk2[k], f2[5]);
      f1[6] = fmaf(q1.z, mk1[k], f1[6]); f2[6] = fmaf(r1.z, mk2[k], f2[6]);
      f1[7] = fmaf(q1.w, mk1[k], f1[7]); f2[7] = fmaf(r1.w, mk2[k], f2[7]);
    }
    float l01 = 0.f, l11 = 0.f, l02 = 0.f, l12 = 0.f;
    const int b1 = b0 + gg, b2 = b0 + gg + 8;
    float* fg1 = out + 2 * (size_t)B_TOTAL + (size_t)b1 * 64;
    float* fg2 = out + 2 * (size_t)B_TOTAL + (size_t)b2 * 64;
#pragma unroll
    for (int i = 0; i < 8; ++i) {
      fg1[i * 8 + e] = f1[i];
      fg2[i * 8 + e] = f2[i];
      l01 = fmaf(f1[i], fcs[(i * 8 + e) * 2 + 0], l01);
      l11 = fmaf(f1[i], fcs[(i * 8 + e) * 2 + 1], l11);
      l02 = fmaf(f2[i], fcs[(i * 8 + e) * 2 + 0], l02);
      l12 = fmaf(f2[i], fcs[(i * 8 + e) * 2 + 1], l12);
    }
    l01 += sx<1>(l01); l01 += sx<2>(l01); l01 += sx<4>(l01);
    l11 += sx<1>(l11); l11 += sx<2>(l11); l11 += sx<4>(l11);
    l02 += sx<1>(l02); l02 += sx<2>(l02); l02 += sx<4>(l02);
    l12 += sx<1>(l12); l12 += sx<2>(l12); l12 += sx<4>(l12);
    float mx1 = fmaxf(l01, l11);
    float ls1 = mx1 + logf(expf(l01 - mx1) + expf(l11 - mx1));
    float mx2 = fmaxf(l02, l12);
    float ls2 = mx2 + logf(expf(l02 - mx2) + expf(l12 - mx2));
    if (e < 2) {
      out[(size_t)b1 * 2 + e] = (e ? l11 : l01) - ls1;
      out[(size_t)b2 * 2 + e] = (e ? l12 : l02) - ls2;
    }
  }
}

extern "C" void kernel_launch(void* const* d_in, const int* in_sizes, int n_in,
                              void* d_out, int out_size, void* d_ws, size_t ws_size,
                              hipStream_t stream) {
  const float* X  = (const float*)d_in[0];   // [8192,62,62]
  const float* w1 = (const float*)d_in[1];   // [62,8]
  const float* w2 = (const float*)d_in[2];   // [8,8]
  const float* fc = (const float*)d_in[3];   // [64,2]
  float* out = (float*)d_out;                // [8192*2] ++ [8192*64]

  spdnet_kernel<<<B_TOTAL / NBB, 128, 0, stream>>>(X, w1, w2, fc, out);
}